// Round 1
// baseline (198.226 us; speedup 1.0000x reference)
//
#include <hip/hip_runtime.h>
#include <math.h>

#define KS 63
#define RAD 31
#define NB 8
#define NC 3
#define NH 512
#define NW 512
#define PADH 576   // 32 zero rows + 512 + 32 zero rows

struct GaussW { float w[KS]; };

// Horizontal 63-tap blur of (noise*2-1), zero padding, written into a
// row-padded scratch [NB*2, 576, 512] in d_ws (rows 0..31, 544..575 zeroed).
// NOTE (R4): hipLaunchCooperativeKernel fails under the harness's graph
// capture (kernel silently never runs) — keep the 2-dispatch structure.
__global__ __launch_bounds__(256) void hblur_kernel(const float* __restrict__ noise,
                                                    float* __restrict__ tmp, GaussW gw) {
    const int bid = blockIdx.x;
    const int t = threadIdx.x;
    if (bid >= NB * NH) {                      // ---- pad-zero path ----
        const int pid = bid - NB * NH;         // [0, 512)
        const int img = pid >> 5;              // 16 planes
        const int pr  = pid & 31;              // 32 row-pairs per plane
        const int row = (pr < 16) ? (pr * 2) : (544 + (pr - 16) * 2);
        float4* dst = (float4*)(tmp + ((size_t)img * PADH + row) * NW);
        dst[t] = make_float4(0.f, 0.f, 0.f, 0.f);   // 256 * 16B = 2 rows
        return;
    }
    // ---- compute path ----
    const int b = bid >> 9;
    const int h = bid & (NH - 1);
    const int ch = t >> 7;                     // waves 0,1 -> ch0; 2,3 -> ch1
    const int tt = t & 127;

    __shared__ float rows[2][PADH];
    const float* src = noise + ((size_t)(b * 2 + ch) * NH + h) * NW;
    {
        const float4 nv = *(const float4*)(src + 4 * tt);
        float4 sv;
        sv.x = fmaf(nv.x, 2.f, -1.f); sv.y = fmaf(nv.y, 2.f, -1.f);
        sv.z = fmaf(nv.z, 2.f, -1.f); sv.w = fmaf(nv.w, 2.f, -1.f);
        *(float4*)&rows[ch][32 + 4 * tt] = sv;
        if (tt < 8) {
            *(float4*)&rows[ch][4 * tt]       = make_float4(0.f, 0.f, 0.f, 0.f);
            *(float4*)&rows[ch][544 + 4 * tt] = make_float4(0.f, 0.f, 0.f, 0.f);
        }
    }
    __syncthreads();

    float acc[4] = {0.f, 0.f, 0.f, 0.f};
#pragma unroll
    for (int c = 0; c < 17; ++c) {
        const float4 v = *(const float4*)&rows[ch][4 * tt + 4 * c];
        const float vv[4] = {v.x, v.y, v.z, v.w};
#pragma unroll
        for (int e = 0; e < 4; ++e) {
#pragma unroll
            for (int oo = 0; oo < 4; ++oo) {
                const int j = 4 * c + e - oo - 1;   // compile-time tap index
                if (j >= 0 && j < KS) acc[oo] = fmaf(vv[e], gw.w[j], acc[oo]);
            }
        }
    }
    float4* dst = (float4*)(tmp + (((size_t)(b * 2 + ch) * PADH) + 32 + h) * NW + 4 * tt);
    *dst = make_float4(acc[0], acc[1], acc[2], acc[3]);
}

// Fused: vertical 63-tap blur -> disp write -> bilinear grid_sample.
// R5 (this round): 4 rows/thread instead of 8. Rationale: latency-bound
// (Occupancy 20%, VALUBusy 13%, 2.0 TB/s = 25% of HBM achievable). 4 rows
// doubles the wave supply to 8192 (32 waves/CU = HW cap) and drops the
// accumulator count so VGPR fits <=64 (__launch_bounds__(256,8)).
// Extra vertical-tap redundancy (16.5 vs 8.75 loads/output) is absorbed by
// L2/L3 — we are far from any BW ceiling.
// XCD swizzle (T1): remap so each XCD owns exactly one batch image; the
// 62/66-row overlap between vertically adjacent blocks becomes L2-local.
__global__ __launch_bounds__(256, 8) void vwarp_kernel(const float* __restrict__ tmp,
                                                       const float* __restrict__ img,
                                                       float2* __restrict__ disp,
                                                       float* __restrict__ warped,
                                                       GaussW gw) {
    const int t = threadIdx.x;
    int bid = blockIdx.x;                      // 2048 blocks
    bid = (bid & 7) * 256 + (bid >> 3);        // XCD-contiguous remap (bijective, 2048%8==0)
    const int wt = bid & 1;
    const int ht = (bid >> 1) & 127;
    const int b  = bid >> 8;
    const int w  = wt * 256 + t;
    const int h0 = ht * 4;

    const float* c0 = tmp + (((size_t)(b * 2 + 0) * PADH) + h0 + 1) * NW + w;
    const float* c1 = tmp + (((size_t)(b * 2 + 1) * PADH) + h0 + 1) * NW + w;

    float ax[4] = {0.f, 0.f, 0.f, 0.f};
    float ay[4] = {0.f, 0.f, 0.f, 0.f};
#pragma unroll
    for (int rr = 0; rr < 66; ++rr) {
        const float vx = c0[(size_t)rr * NW];
        const float vy = c1[(size_t)rr * NW];
#pragma unroll
        for (int o = 0; o < 4; ++o) {
            const int j = rr - o;              // compile-time tap index
            if (j >= 0 && j < KS) {
                ax[o] = fmaf(vx, gw.w[j], ax[o]);
                ay[o] = fmaf(vy, gw.w[j], ay[o]);
            }
        }
    }

    const float gxb = fmaf((float)w, 2.0f / 511.0f, -1.0f);
    const float* i0 = img + (size_t)b * NC * NH * NW;
    const float* i1 = i0 + NH * NW;
    const float* i2 = i1 + NH * NW;
    float* wp = warped + (size_t)b * NC * NH * NW;

#pragma unroll
    for (int o = 0; o < 4; ++o) {
        const int h = h0 + o;
        disp[((size_t)b * NH + h) * NW + w] = make_float2(ax[o], ay[o]);

        float gx = gxb + ax[o];
        float gy = fmaf((float)h, 2.0f / 511.0f, -1.0f) + ay[o];
        gx = fminf(1.f, fmaxf(-1.f, gx));
        gy = fminf(1.f, fmaxf(-1.f, gy));

        const float x = ((gx + 1.0f) * (float)NW - 1.0f) * 0.5f;
        const float y = ((gy + 1.0f) * (float)NH - 1.0f) * 0.5f;
        const float xf = floorf(x), yf = floorf(y);
        const int x0 = (int)xf, y0 = (int)yf;
        const int x1 = x0 + 1,  y1 = y0 + 1;
        const float wx1 = x - xf, wx0 = 1.0f - wx1;
        const float wy1 = y - yf, wy0 = 1.0f - wy1;
        // validity folded into weights (no divergent conditional loads)
        const float fx0 = ((unsigned)x0 < NW) ? 1.f : 0.f;
        const float fx1 = ((unsigned)x1 < NW) ? 1.f : 0.f;
        const float fy0 = ((unsigned)y0 < NH) ? 1.f : 0.f;
        const float fy1 = ((unsigned)y1 < NH) ? 1.f : 0.f;
        const int x0c = min(max(x0, 0), NW - 1), x1c = min(max(x1, 0), NW - 1);
        const int y0c = min(max(y0, 0), NH - 1), y1c = min(max(y1, 0), NH - 1);
        const float w00 = wy0 * wx0 * (fy0 * fx0), w01 = wy0 * wx1 * (fy0 * fx1);
        const float w10 = wy1 * wx0 * (fy1 * fx0), w11 = wy1 * wx1 * (fy1 * fx1);
        const int o00 = y0c * NW + x0c, o01 = y0c * NW + x1c;
        const int o10 = y1c * NW + x0c, o11 = y1c * NW + x1c;
        const size_t po = (size_t)h * NW + w;
        wp[po]               = ((i0[o00] * w00 + i0[o01] * w01) + i0[o10] * w10) + i0[o11] * w11;
        wp[NH * NW + po]     = ((i1[o00] * w00 + i1[o01] * w01) + i1[o10] * w10) + i1[o11] * w11;
        wp[2 * NH * NW + po] = ((i2[o00] * w00 + i2[o01] * w01) + i2[o10] * w10) + i2[o11] * w11;
    }
}

extern "C" void kernel_launch(void* const* d_in, const int* in_sizes, int n_in,
                              void* d_out, int out_size, void* d_ws, size_t ws_size,
                              hipStream_t stream) {
    const float* image = (const float*)d_in[0];  // [8,3,512,512] fp32
    const float* noise = (const float*)d_in[1];  // [8,2,512,512] fp32
    float* warped = (float*)d_out;                               // [8,3,512,512]
    float* dispo  = (float*)d_out + (size_t)NB * NC * NH * NW;   // [8,512,512,2]
    float* scratch = (float*)d_ws;   // [NB*2, 576, 512] = 18.9 MB, pad rows re-zeroed each call

    GaussW gw;
    float s = 0.f;
    for (int i = 0; i < KS; ++i) {
        const float xv = (float)(i - RAD);
        gw.w[i] = expf(-(xv * xv) / (2.0f * 32.0f * 32.0f));
        s += gw.w[i];
    }
    for (int i = 0; i < KS; ++i) gw.w[i] /= s;

    hblur_kernel<<<NB * NH + 512, 256, 0, stream>>>(noise, scratch, gw);
    vwarp_kernel<<<NB * (NH / 4) * 2, 256, 0, stream>>>(scratch, image,
                                                        (float2*)dispo, warped, gw);
}

// Round 2
// 147.809 us; speedup vs baseline: 1.3411x; 1.3411x over previous
//
#include <hip/hip_runtime.h>
#include <math.h>

#define KS 63
#define RAD 31
#define NB 8
#define NC 3
#define NH 512
#define NW 512
#define PADH 576   // 32 zero rows + 512 + 32 zero rows

struct GaussW { float w[KS]; };

// Horizontal 63-tap blur of (noise*2-1), zero padding, written into a
// row-padded scratch [NB*2, 576, 512] in d_ws (rows 0..31, 544..575 zeroed).
// NOTE (R4): hipLaunchCooperativeKernel fails under the harness's graph
// capture (kernel silently never runs) — keep the 2-dispatch structure.
__global__ __launch_bounds__(256) void hblur_kernel(const float* __restrict__ noise,
                                                    float* __restrict__ tmp, GaussW gw) {
    const int bid = blockIdx.x;
    const int t = threadIdx.x;
    if (bid >= NB * NH) {                      // ---- pad-zero path ----
        const int pid = bid - NB * NH;         // [0, 512)
        const int img = pid >> 5;              // 16 planes
        const int pr  = pid & 31;              // 32 row-pairs per plane
        const int row = (pr < 16) ? (pr * 2) : (544 + (pr - 16) * 2);
        float4* dst = (float4*)(tmp + ((size_t)img * PADH + row) * NW);
        dst[t] = make_float4(0.f, 0.f, 0.f, 0.f);   // 256 * 16B = 2 rows
        return;
    }
    // ---- compute path ----
    const int b = bid >> 9;
    const int h = bid & (NH - 1);
    const int ch = t >> 7;                     // waves 0,1 -> ch0; 2,3 -> ch1
    const int tt = t & 127;

    __shared__ float rows[2][PADH];
    const float* src = noise + ((size_t)(b * 2 + ch) * NH + h) * NW;
    {
        const float4 nv = *(const float4*)(src + 4 * tt);
        float4 sv;
        sv.x = fmaf(nv.x, 2.f, -1.f); sv.y = fmaf(nv.y, 2.f, -1.f);
        sv.z = fmaf(nv.z, 2.f, -1.f); sv.w = fmaf(nv.w, 2.f, -1.f);
        *(float4*)&rows[ch][32 + 4 * tt] = sv;
        if (tt < 8) {
            *(float4*)&rows[ch][4 * tt]       = make_float4(0.f, 0.f, 0.f, 0.f);
            *(float4*)&rows[ch][544 + 4 * tt] = make_float4(0.f, 0.f, 0.f, 0.f);
        }
    }
    __syncthreads();

    float acc[4] = {0.f, 0.f, 0.f, 0.f};
#pragma unroll
    for (int c = 0; c < 17; ++c) {
        const float4 v = *(const float4*)&rows[ch][4 * tt + 4 * c];
        const float vv[4] = {v.x, v.y, v.z, v.w};
#pragma unroll
        for (int e = 0; e < 4; ++e) {
#pragma unroll
            for (int oo = 0; oo < 4; ++oo) {
                const int j = 4 * c + e - oo - 1;   // compile-time tap index
                if (j >= 0 && j < KS) acc[oo] = fmaf(vv[e], gw.w[j], acc[oo]);
            }
        }
    }
    float4* dst = (float4*)(tmp + (((size_t)(b * 2 + ch) * PADH) + 32 + h) * NW + 4 * tt);
    *dst = make_float4(acc[0], acc[1], acc[2], acc[3]);
}

// Fused: vertical 63-tap blur -> disp write -> bilinear grid_sample.
// R5: 4 rows/thread (wave supply 8192 = 32/CU cap) + XCD swizzle.
// R6 (this round): __launch_bounds__(256,8) forced VGPR=32 -> scratch spills
// (+162MB WRITE, +55MB FETCH, VALUBusy 8.7%, 103us). Relax to (256,4):
// VGPR cap 128, compiler lands ~56-64 naturally -> 6-8 waves/EU, no spill.
__global__ __launch_bounds__(256, 4) void vwarp_kernel(const float* __restrict__ tmp,
                                                       const float* __restrict__ img,
                                                       float2* __restrict__ disp,
                                                       float* __restrict__ warped,
                                                       GaussW gw) {
    const int t = threadIdx.x;
    int bid = blockIdx.x;                      // 2048 blocks
    bid = (bid & 7) * 256 + (bid >> 3);        // XCD-contiguous remap (bijective, 2048%8==0)
    const int wt = bid & 1;
    const int ht = (bid >> 1) & 127;
    const int b  = bid >> 8;
    const int w  = wt * 256 + t;
    const int h0 = ht * 4;

    const float* c0 = tmp + (((size_t)(b * 2 + 0) * PADH) + h0 + 1) * NW + w;
    const float* c1 = tmp + (((size_t)(b * 2 + 1) * PADH) + h0 + 1) * NW + w;

    float ax[4] = {0.f, 0.f, 0.f, 0.f};
    float ay[4] = {0.f, 0.f, 0.f, 0.f};
#pragma unroll
    for (int rr = 0; rr < 66; ++rr) {
        const float vx = c0[(size_t)rr * NW];
        const float vy = c1[(size_t)rr * NW];
#pragma unroll
        for (int o = 0; o < 4; ++o) {
            const int j = rr - o;              // compile-time tap index
            if (j >= 0 && j < KS) {
                ax[o] = fmaf(vx, gw.w[j], ax[o]);
                ay[o] = fmaf(vy, gw.w[j], ay[o]);
            }
        }
    }

    const float gxb = fmaf((float)w, 2.0f / 511.0f, -1.0f);
    const float* i0 = img + (size_t)b * NC * NH * NW;
    const float* i1 = i0 + NH * NW;
    const float* i2 = i1 + NH * NW;
    float* wp = warped + (size_t)b * NC * NH * NW;

#pragma unroll
    for (int o = 0; o < 4; ++o) {
        const int h = h0 + o;
        disp[((size_t)b * NH + h) * NW + w] = make_float2(ax[o], ay[o]);

        float gx = gxb + ax[o];
        float gy = fmaf((float)h, 2.0f / 511.0f, -1.0f) + ay[o];
        gx = fminf(1.f, fmaxf(-1.f, gx));
        gy = fminf(1.f, fmaxf(-1.f, gy));

        const float x = ((gx + 1.0f) * (float)NW - 1.0f) * 0.5f;
        const float y = ((gy + 1.0f) * (float)NH - 1.0f) * 0.5f;
        const float xf = floorf(x), yf = floorf(y);
        const int x0 = (int)xf, y0 = (int)yf;
        const int x1 = x0 + 1,  y1 = y0 + 1;
        const float wx1 = x - xf, wx0 = 1.0f - wx1;
        const float wy1 = y - yf, wy0 = 1.0f - wy1;
        // validity folded into weights (no divergent conditional loads)
        const float fx0 = ((unsigned)x0 < NW) ? 1.f : 0.f;
        const float fx1 = ((unsigned)x1 < NW) ? 1.f : 0.f;
        const float fy0 = ((unsigned)y0 < NH) ? 1.f : 0.f;
        const float fy1 = ((unsigned)y1 < NH) ? 1.f : 0.f;
        const int x0c = min(max(x0, 0), NW - 1), x1c = min(max(x1, 0), NW - 1);
        const int y0c = min(max(y0, 0), NH - 1), y1c = min(max(y1, 0), NH - 1);
        const float w00 = wy0 * wx0 * (fy0 * fx0), w01 = wy0 * wx1 * (fy0 * fx1);
        const float w10 = wy1 * wx0 * (fy1 * fx0), w11 = wy1 * wx1 * (fy1 * fx1);
        const int o00 = y0c * NW + x0c, o01 = y0c * NW + x1c;
        const int o10 = y1c * NW + x0c, o11 = y1c * NW + x1c;
        const size_t po = (size_t)h * NW + w;
        wp[po]               = ((i0[o00] * w00 + i0[o01] * w01) + i0[o10] * w10) + i0[o11] * w11;
        wp[NH * NW + po]     = ((i1[o00] * w00 + i1[o01] * w01) + i1[o10] * w10) + i1[o11] * w11;
        wp[2 * NH * NW + po] = ((i2[o00] * w00 + i2[o01] * w01) + i2[o10] * w10) + i2[o11] * w11;
    }
}

extern "C" void kernel_launch(void* const* d_in, const int* in_sizes, int n_in,
                              void* d_out, int out_size, void* d_ws, size_t ws_size,
                              hipStream_t stream) {
    const float* image = (const float*)d_in[0];  // [8,3,512,512] fp32
    const float* noise = (const float*)d_in[1];  // [8,2,512,512] fp32
    float* warped = (float*)d_out;                               // [8,3,512,512]
    float* dispo  = (float*)d_out + (size_t)NB * NC * NH * NW;   // [8,512,512,2]
    float* scratch = (float*)d_ws;   // [NB*2, 576, 512] = 18.9 MB, pad rows re-zeroed each call

    GaussW gw;
    float s = 0.f;
    for (int i = 0; i < KS; ++i) {
        const float xv = (float)(i - RAD);
        gw.w[i] = expf(-(xv * xv) / (2.0f * 32.0f * 32.0f));
        s += gw.w[i];
    }
    for (int i = 0; i < KS; ++i) gw.w[i] /= s;

    hblur_kernel<<<NB * NH + 512, 256, 0, stream>>>(noise, scratch, gw);
    vwarp_kernel<<<NB * (NH / 4) * 2, 256, 0, stream>>>(scratch, image,
                                                        (float2*)dispo, warped, gw);
}

// Round 3
// 136.252 us; speedup vs baseline: 1.4548x; 1.0848x over previous
//
#include <hip/hip_runtime.h>
#include <math.h>

#define KS 63
#define RAD 31
#define NB 8
#define NC 3
#define NH 512
#define NW 512
#define PADH 576   // 32 zero rows + 512 + 32 zero rows

struct GaussW { float w[KS]; };

// Horizontal 63-tap blur of (noise*2-1), zero padding, written into a
// row-padded scratch [NB*2, 576, 512] in d_ws (rows 0..31, 544..575 zeroed).
// NOTE (R4): hipLaunchCooperativeKernel fails under the harness's graph
// capture (kernel silently never runs) — keep the 2-dispatch structure.
__global__ __launch_bounds__(256) void hblur_kernel(const float* __restrict__ noise,
                                                    float* __restrict__ tmp, GaussW gw) {
    const int bid = blockIdx.x;
    const int t = threadIdx.x;
    if (bid >= NB * NH) {                      // ---- pad-zero path ----
        const int pid = bid - NB * NH;         // [0, 512)
        const int img = pid >> 5;              // 16 planes
        const int pr  = pid & 31;              // 32 row-pairs per plane
        const int row = (pr < 16) ? (pr * 2) : (544 + (pr - 16) * 2);
        float4* dst = (float4*)(tmp + ((size_t)img * PADH + row) * NW);
        dst[t] = make_float4(0.f, 0.f, 0.f, 0.f);   // 256 * 16B = 2 rows
        return;
    }
    // ---- compute path ----
    const int b = bid >> 9;
    const int h = bid & (NH - 1);
    const int ch = t >> 7;                     // waves 0,1 -> ch0; 2,3 -> ch1
    const int tt = t & 127;

    __shared__ float rows[2][PADH];
    const float* src = noise + ((size_t)(b * 2 + ch) * NH + h) * NW;
    {
        const float4 nv = *(const float4*)(src + 4 * tt);
        float4 sv;
        sv.x = fmaf(nv.x, 2.f, -1.f); sv.y = fmaf(nv.y, 2.f, -1.f);
        sv.z = fmaf(nv.z, 2.f, -1.f); sv.w = fmaf(nv.w, 2.f, -1.f);
        *(float4*)&rows[ch][32 + 4 * tt] = sv;
        if (tt < 8) {
            *(float4*)&rows[ch][4 * tt]       = make_float4(0.f, 0.f, 0.f, 0.f);
            *(float4*)&rows[ch][544 + 4 * tt] = make_float4(0.f, 0.f, 0.f, 0.f);
        }
    }
    __syncthreads();

    float acc[4] = {0.f, 0.f, 0.f, 0.f};
#pragma unroll
    for (int c = 0; c < 17; ++c) {
        const float4 v = *(const float4*)&rows[ch][4 * tt + 4 * c];
        const float vv[4] = {v.x, v.y, v.z, v.w};
#pragma unroll
        for (int e = 0; e < 4; ++e) {
#pragma unroll
            for (int oo = 0; oo < 4; ++oo) {
                const int j = 4 * c + e - oo - 1;   // compile-time tap index
                if (j >= 0 && j < KS) acc[oo] = fmaf(vv[e], gw.w[j], acc[oo]);
            }
        }
    }
    float4* dst = (float4*)(tmp + (((size_t)(b * 2 + ch) * PADH) + 32 + h) * NW + 4 * tt);
    *dst = make_float4(acc[0], acc[1], acc[2], acc[3]);
}

// Fused: vertical 63-tap blur -> disp write -> bilinear grid_sample.
// R5: 4 rows/thread (wave supply 8192 = 32/CU cap) + XCD swizzle.
// R6: __launch_bounds__(256,8) -> VGPR=32, massive spill (103us).
// R7 (this round): (256,4) still pinned VGPR to the 64 boundary with a mild
// spill (+27MB WRITE_SIZE, 53.5us). Plain __launch_bounds__(256): compiler's
// natural ~76 VGPR, spill-free (proven in R0), now combined with the 8192-wave
// supply -> occupancy register-bound at ~5-6 waves/EU instead of grid-bound.
__global__ __launch_bounds__(256) void vwarp_kernel(const float* __restrict__ tmp,
                                                    const float* __restrict__ img,
                                                    float2* __restrict__ disp,
                                                    float* __restrict__ warped,
                                                    GaussW gw) {
    const int t = threadIdx.x;
    int bid = blockIdx.x;                      // 2048 blocks
    bid = (bid & 7) * 256 + (bid >> 3);        // XCD-contiguous remap (bijective, 2048%8==0)
    const int wt = bid & 1;
    const int ht = (bid >> 1) & 127;
    const int b  = bid >> 8;
    const int w  = wt * 256 + t;
    const int h0 = ht * 4;

    const float* c0 = tmp + (((size_t)(b * 2 + 0) * PADH) + h0 + 1) * NW + w;
    const float* c1 = tmp + (((size_t)(b * 2 + 1) * PADH) + h0 + 1) * NW + w;

    float ax[4] = {0.f, 0.f, 0.f, 0.f};
    float ay[4] = {0.f, 0.f, 0.f, 0.f};
#pragma unroll
    for (int rr = 0; rr < 66; ++rr) {
        const float vx = c0[(size_t)rr * NW];
        const float vy = c1[(size_t)rr * NW];
#pragma unroll
        for (int o = 0; o < 4; ++o) {
            const int j = rr - o;              // compile-time tap index
            if (j >= 0 && j < KS) {
                ax[o] = fmaf(vx, gw.w[j], ax[o]);
                ay[o] = fmaf(vy, gw.w[j], ay[o]);
            }
        }
    }

    const float gxb = fmaf((float)w, 2.0f / 511.0f, -1.0f);
    const float* i0 = img + (size_t)b * NC * NH * NW;
    const float* i1 = i0 + NH * NW;
    const float* i2 = i1 + NH * NW;
    float* wp = warped + (size_t)b * NC * NH * NW;

#pragma unroll
    for (int o = 0; o < 4; ++o) {
        const int h = h0 + o;
        disp[((size_t)b * NH + h) * NW + w] = make_float2(ax[o], ay[o]);

        float gx = gxb + ax[o];
        float gy = fmaf((float)h, 2.0f / 511.0f, -1.0f) + ay[o];
        gx = fminf(1.f, fmaxf(-1.f, gx));
        gy = fminf(1.f, fmaxf(-1.f, gy));

        const float x = ((gx + 1.0f) * (float)NW - 1.0f) * 0.5f;
        const float y = ((gy + 1.0f) * (float)NH - 1.0f) * 0.5f;
        const float xf = floorf(x), yf = floorf(y);
        const int x0 = (int)xf, y0 = (int)yf;
        const int x1 = x0 + 1,  y1 = y0 + 1;
        const float wx1 = x - xf, wx0 = 1.0f - wx1;
        const float wy1 = y - yf, wy0 = 1.0f - wy1;
        // validity folded into weights (no divergent conditional loads)
        const float fx0 = ((unsigned)x0 < NW) ? 1.f : 0.f;
        const float fx1 = ((unsigned)x1 < NW) ? 1.f : 0.f;
        const float fy0 = ((unsigned)y0 < NH) ? 1.f : 0.f;
        const float fy1 = ((unsigned)y1 < NH) ? 1.f : 0.f;
        const int x0c = min(max(x0, 0), NW - 1), x1c = min(max(x1, 0), NW - 1);
        const int y0c = min(max(y0, 0), NH - 1), y1c = min(max(y1, 0), NH - 1);
        const float w00 = wy0 * wx0 * (fy0 * fx0), w01 = wy0 * wx1 * (fy0 * fx1);
        const float w10 = wy1 * wx0 * (fy1 * fx0), w11 = wy1 * wx1 * (fy1 * fx1);
        const int o00 = y0c * NW + x0c, o01 = y0c * NW + x1c;
        const int o10 = y1c * NW + x0c, o11 = y1c * NW + x1c;
        const size_t po = (size_t)h * NW + w;
        wp[po]               = ((i0[o00] * w00 + i0[o01] * w01) + i0[o10] * w10) + i0[o11] * w11;
        wp[NH * NW + po]     = ((i1[o00] * w00 + i1[o01] * w01) + i1[o10] * w10) + i1[o11] * w11;
        wp[2 * NH * NW + po] = ((i2[o00] * w00 + i2[o01] * w01) + i2[o10] * w10) + i2[o11] * w11;
    }
}

extern "C" void kernel_launch(void* const* d_in, const int* in_sizes, int n_in,
                              void* d_out, int out_size, void* d_ws, size_t ws_size,
                              hipStream_t stream) {
    const float* image = (const float*)d_in[0];  // [8,3,512,512] fp32
    const float* noise = (const float*)d_in[1];  // [8,2,512,512] fp32
    float* warped = (float*)d_out;                               // [8,3,512,512]
    float* dispo  = (float*)d_out + (size_t)NB * NC * NH * NW;   // [8,512,512,2]
    float* scratch = (float*)d_ws;   // [NB*2, 576, 512] = 18.9 MB, pad rows re-zeroed each call

    GaussW gw;
    float s = 0.f;
    for (int i = 0; i < KS; ++i) {
        const float xv = (float)(i - RAD);
        gw.w[i] = expf(-(xv * xv) / (2.0f * 32.0f * 32.0f));
        s += gw.w[i];
    }
    for (int i = 0; i < KS; ++i) gw.w[i] /= s;

    hblur_kernel<<<NB * NH + 512, 256, 0, stream>>>(noise, scratch, gw);
    vwarp_kernel<<<NB * (NH / 4) * 2, 256, 0, stream>>>(scratch, image,
                                                        (float2*)dispo, warped, gw);
}